// Round 10
// baseline (111.565 us; speedup 1.0000x reference)
//
#include <hip/hip_runtime.h>

#define NPTS 1000000
#define OUT_STRIDE (9 * NPTS)

// Scales order: [2, 4, 8, 16, 1]; dims = ceil(SPATIAL/scale)+1
constexpr int   kSX[5]  = {241, 121, 61, 31, 481};
constexpr int   kSY[5]  = {181,  91, 46, 24, 361};
constexpr int   kSZ[5]  = { 17,   9,  5,  3,  33};
constexpr float kSSX[5] = {240.f, 120.f, 60.f, 30.f, 480.f};
constexpr float kSSY[5] = {180.f,  90.f, 45.f, 23.f, 360.f};
constexpr float kSSZ[5] = { 16.f,   8.f,  4.f,  2.f,  32.f};
// word-bases of each scale's bitmap region (keyspace/32, rounded up to 64)
constexpr int kWB[5] = {0, 92736, 105152, 106944, 107264};
#define W_TOTAL 823552        // 107264 + 716288
#define SCAN_BLOCKS 403       // ceil(W_TOTAL / 2048)

// byte map = exact 32x expansion of the bit map: byte index = word*32 + bit.
#define BM_BYTES ((size_t)W_TOTAL * 32)     // 26,353,664 B
#define BM_U4    (BM_BYTES / 16)            // 1,647,104 uint4

// emit kernel block ranges (256 threads each)
#define SCAT_BLOCKS 3217    // ceil(W_TOTAL / 256)
#define PAD_BLOCKS  19532   // ceil(5*NPTS / 256)
#define INV_BLOCKS  3907    // ceil(NPTS / 256)
#define EMIT_BLOCKS (SCAT_BLOCKS + PAD_BLOCKS + INV_BLOCKS)

// ---- zero the byte map
__global__ void zero_kernel(uint4* __restrict__ p) {
  size_t i = (size_t)blockIdx.x * 256 + threadIdx.x;
  if (i < BM_U4) p[i] = make_uint4(0u, 0u, 0u, 0u);
}

// ---- mark: polar once per point; bxyz out; 5 idempotent byte stores
__global__ void mark_kernel(const float4* __restrict__ pts,
                            const int* __restrict__ bidx,
                            int* __restrict__ out,
                            unsigned char* __restrict__ bytemap) {
  int i = blockIdx.x * 256 + threadIdx.x;
  if (i >= NPTS) return;
  float4 p = pts[i];
  float rho = __fsqrt_rn(__fadd_rn(__fmul_rn(p.x, p.x), __fmul_rn(p.y, p.y)));
  float phi = (float)atan2((double)p.y, (double)p.x);
  float zz = p.z;
  int b = bidx[i];
  const float PI_F = 3.14159265f;
  const float CROP1 = PI_F + PI_F;
#pragma unroll
  for (int s = 0; s < 5; ++s) {
    int ix = (int)__fdiv_rn(__fmul_rn(kSSX[s], rho), 50.0f);
    int iy = (int)__fdiv_rn(__fmul_rn(kSSY[s], __fsub_rn(phi, -PI_F)), CROP1);
    int iz = (int)__fdiv_rn(__fmul_rn(kSSZ[s], __fsub_rn(zz, -4.0f)), 6.0f);
    int key = ((b * kSX[s] + ix) * kSY[s] + iy) * kSZ[s] + iz;
    ((int4*)(out + (size_t)s * OUT_STRIDE))[i] = make_int4(b, ix, iy, iz);
    bytemap[(size_t)kWB[s] * 32 + (unsigned)key] = 1;
  }
}

// 32 presence-bytes (each 0/1) -> 32-bit mask
__device__ __forceinline__ unsigned nib(unsigned u) {
  return (u | (u >> 7) | (u >> 14) | (u >> 21)) & 0xFu;
}
__device__ __forceinline__ unsigned word_from_bytes(const uint4* p) {
  uint4 a = p[0], b = p[1];
  return nib(a.x) | (nib(a.y) << 4) | (nib(a.z) << 8) | (nib(a.w) << 12) |
         (nib(b.x) << 16) | (nib(b.y) << 20) | (nib(b.z) << 24) | (nib(b.w) << 28);
}

// ---- scan stage 1: bytes -> {bits, chunk-local prefix} pairs + raw chunk sums
__global__ void scan1_kernel(const uint4* __restrict__ bytemap,
                             uint2* __restrict__ bw,
                             unsigned* __restrict__ bsums) {
  __shared__ unsigned sh[256];
  int tid = threadIdx.x;
  int base = blockIdx.x * 2048 + tid * 8;
  unsigned c[8], m[8];
  unsigned sum = 0;
#pragma unroll
  for (int j = 0; j < 8; ++j) {
    c[j] = sum;
    int w = base + j;
    m[j] = (w < W_TOTAL) ? word_from_bytes(bytemap + (size_t)w * 2) : 0u;
    sum += (unsigned)__popc(m[j]);
  }
  sh[tid] = sum;
  __syncthreads();
  for (int off = 1; off < 256; off <<= 1) {
    unsigned v = (tid >= off) ? sh[tid - off] : 0u;
    __syncthreads();
    sh[tid] += v;
    __syncthreads();
  }
  unsigned tbase = sh[tid] - sum;
#pragma unroll
  for (int j = 0; j < 8; ++j) {
    int w = base + j;
    if (w < W_TOTAL) bw[w] = make_uint2(m[j], tbase + c[j]);
  }
  if (tid == 0) bsums[blockIdx.x] = sh[255];
}

// ---- emit: per-block wave-synchronous scan of the 403 chunk sums (no extra
//      dispatch), then fused scatter / padfill / inverse using LDS prefixes.
__global__ void emit_kernel(const float4* __restrict__ pts,
                            const int* __restrict__ bidx,
                            const uint2* __restrict__ bw,
                            const unsigned* __restrict__ bsums,
                            int* __restrict__ out) {
  __shared__ unsigned sbs[448];   // scanned (exclusive) chunk sums
  __shared__ unsigned rb[6];      // region base prefix per scale + grand total
  int tid = threadIdx.x;
  if (tid < 64) {                 // wave 0: shuffle-scan, no barriers inside
    int lane = tid;
    unsigned v[7], s = 0;
    int base = lane * 7;          // 64*7 = 448 >= 403
#pragma unroll
    for (int j = 0; j < 7; ++j) {
      int k = base + j;
      v[j] = s;
      s += (k < SCAN_BLOCKS) ? bsums[k] : 0u;
    }
    unsigned e = s;
    for (int off = 1; off < 64; off <<= 1) {
      unsigned u = __shfl_up(e, off);
      if (lane >= off) e += u;
    }
    unsigned bex = e - s;         // exclusive over lanes
#pragma unroll
    for (int j = 0; j < 7; ++j) {
      int k = base + j;
      if (k < 448) sbs[k] = bex + v[j];
    }
    if (lane == 63) rb[5] = e;    // grand total
  }
  __syncthreads();
  if (tid < 5) rb[tid] = bw[kWB[tid]].y + sbs[kWB[tid] >> 11];
  __syncthreads();

  int blk = blockIdx.x;
  if (blk < SCAT_BLOCKS) {
    int w = blk * 256 + tid;
    if (w >= W_TOTAL) return;
    uint2 v = bw[w];
    unsigned word = v.x;
    if (!word) return;
    int s;
    unsigned sx, sy, sz;
    int wb;
    if      (w >= kWB[4]) { s = 4; wb = kWB[4]; sx = 481; sy = 361; sz = 33; }
    else if (w >= kWB[3]) { s = 3; wb = kWB[3]; sx = 31;  sy = 24;  sz = 3;  }
    else if (w >= kWB[2]) { s = 2; wb = kWB[2]; sx = 61;  sy = 46;  sz = 5;  }
    else if (w >= kWB[1]) { s = 1; wb = kWB[1]; sx = 121; sy = 91;  sz = 9;  }
    else                  { s = 0; wb = 0;      sx = 241; sy = 181; sz = 17; }
    unsigned rank = v.y + sbs[w >> 11] - rb[s];
    int4* coors = (int4*)(out + (size_t)s * OUT_STRIDE + 5 * NPTS);
    unsigned kbase = (unsigned)(w - wb) * 32u;
    while (word) {
      int bit = __ffs(word) - 1;
      word &= word - 1;
      unsigned k = kbase + (unsigned)bit;
      unsigned z = k % sz; unsigned t = k / sz;
      unsigned y = t % sy; t /= sy;
      unsigned x = t % sx; unsigned b = t / sx;
      coors[rank++] = make_int4((int)b, (int)z, (int)y, (int)x);
    }
  } else if (blk < SCAT_BLOCKS + PAD_BLOCKS) {
    int idx = (blk - SCAT_BLOCKS) * 256 + tid;
    if (idx >= 5 * NPTS) return;
    int s = idx / NPTS;
    int r = idx - s * NPTS;
    unsigned uniq = ((s == 4) ? rb[5] : rb[s + 1]) - rb[s];
    if ((unsigned)r < uniq) return;
    ((int4*)(out + (size_t)s * OUT_STRIDE + 5 * NPTS))[r] =
        make_int4(-1, kSZ[s] - 1, kSY[s] - 1, kSX[s] - 1);
  } else {
    int i = (blk - SCAT_BLOCKS - PAD_BLOCKS) * 256 + tid;
    if (i >= NPTS) return;
    float4 p = pts[i];
    float rho = __fsqrt_rn(__fadd_rn(__fmul_rn(p.x, p.x), __fmul_rn(p.y, p.y)));
    float phi = (float)atan2((double)p.y, (double)p.x);
    float zz = p.z;
    int b = bidx[i];
    const float PI_F = 3.14159265f;
    const float CROP1 = PI_F + PI_F;
#pragma unroll
    for (int s = 0; s < 5; ++s) {
      int ix = (int)__fdiv_rn(__fmul_rn(kSSX[s], rho), 50.0f);
      int iy = (int)__fdiv_rn(__fmul_rn(kSSY[s], __fsub_rn(phi, -PI_F)), CROP1);
      int iz = (int)__fdiv_rn(__fmul_rn(kSSZ[s], __fsub_rn(zz, -4.0f)), 6.0f);
      unsigned k = (unsigned)(((b * kSX[s] + ix) * kSY[s] + iy) * kSZ[s] + iz);
      int w = kWB[s] + (int)(k >> 5);
      uint2 v = bw[w];                       // one 8B gather: {bits, prefix}
      unsigned r = v.y + sbs[w >> 11] - rb[s] +
                   (unsigned)__popc(v.x & ((1u << (k & 31)) - 1u));
      out[(size_t)s * OUT_STRIDE + 4 * NPTS + i] = (int)r;
    }
  }
}

extern "C" void kernel_launch(void* const* d_in, const int* in_sizes, int n_in,
                              void* d_out, int out_size, void* d_ws, size_t ws_size,
                              hipStream_t stream) {
  const float4* pts = (const float4*)d_in[0];
  const int* bidx = (const int*)d_in[1];
  int* out = (int*)d_out;

  uint2* bw       = (uint2*)d_ws;               // W_TOTAL uint2 (6.6 MB)
  unsigned* bsums = (unsigned*)(bw + W_TOTAL);  // 512 u32 raw chunk sums
  unsigned char* bytemap = (unsigned char*)(bsums + 1024);  // 26.4 MB
  // total ws use: ~33 MB (proven available)

  zero_kernel<<<(int)((BM_U4 + 255) / 256), 256, 0, stream>>>((uint4*)bytemap);
  mark_kernel<<<(NPTS + 255) / 256, 256, 0, stream>>>(pts, bidx, out, bytemap);
  scan1_kernel<<<SCAN_BLOCKS, 256, 0, stream>>>((const uint4*)bytemap, bw, bsums);
  emit_kernel<<<EMIT_BLOCKS, 256, 0, stream>>>(pts, bidx, bw, bsums, out);
}

// Round 11
// 106.793 us; speedup vs baseline: 1.0447x; 1.0447x over previous
//
#include <hip/hip_runtime.h>

#define NPTS 1000000
#define OUT_STRIDE (9 * NPTS)

// Scales order: [2, 4, 8, 16, 1]; dims = ceil(SPATIAL/scale)+1
constexpr int   kSX[5]  = {241, 121, 61, 31, 481};
constexpr int   kSY[5]  = {181,  91, 46, 24, 361};
constexpr int   kSZ[5]  = { 17,   9,  5,  3,  33};
constexpr float kSSX[5] = {240.f, 120.f, 60.f, 30.f, 480.f};
constexpr float kSSY[5] = {180.f,  90.f, 45.f, 23.f, 360.f};
constexpr float kSSZ[5] = { 16.f,   8.f,  4.f,  2.f,  32.f};
// word-bases of each scale's bitmap region (keyspace/32, rounded up to 64)
constexpr int kWB[5] = {0, 92736, 105152, 106944, 107264};
#define W_TOTAL 823552        // 107264 + 716288
#define SCAN_BLOCKS 403       // ceil(W_TOTAL / 2048)

// byte map = exact 32x expansion of the bit map: byte index = word*32 + bit.
#define BM_BYTES ((size_t)W_TOTAL * 32)     // 26,353,664 B
#define BM_U4    (BM_BYTES / 16)            // 1,647,104 uint4

// emit kernel block ranges (256 threads each); order: inv | scatter | padfill
#define INV_BLOCKS  3907    // ceil(NPTS / 256)
#define SCAT_BLOCKS 3217    // ceil(W_TOTAL / 256)
#define PAD_BLOCKS  19532   // ceil(5*NPTS / 256)
#define EMIT_BLOCKS (INV_BLOCKS + SCAT_BLOCKS + PAD_BLOCKS)

// ---- zero the byte map
__global__ void zero_kernel(uint4* __restrict__ p) {
  size_t i = (size_t)blockIdx.x * 256 + threadIdx.x;
  if (i < BM_U4) p[i] = make_uint4(0u, 0u, 0u, 0u);
}

// ---- mark: polar once per point; bxyz out; 5 idempotent byte stores
__global__ void mark_kernel(const float4* __restrict__ pts,
                            const int* __restrict__ bidx,
                            int* __restrict__ out,
                            unsigned char* __restrict__ bytemap) {
  int i = blockIdx.x * 256 + threadIdx.x;
  if (i >= NPTS) return;
  float4 p = pts[i];
  float rho = __fsqrt_rn(__fadd_rn(__fmul_rn(p.x, p.x), __fmul_rn(p.y, p.y)));
  float phi = (float)atan2((double)p.y, (double)p.x);
  float zz = p.z;
  int b = bidx[i];
  const float PI_F = 3.14159265f;
  const float CROP1 = PI_F + PI_F;
#pragma unroll
  for (int s = 0; s < 5; ++s) {
    int ix = (int)__fdiv_rn(__fmul_rn(kSSX[s], rho), 50.0f);
    int iy = (int)__fdiv_rn(__fmul_rn(kSSY[s], __fsub_rn(phi, -PI_F)), CROP1);
    int iz = (int)__fdiv_rn(__fmul_rn(kSSZ[s], __fsub_rn(zz, -4.0f)), 6.0f);
    int key = ((b * kSX[s] + ix) * kSY[s] + iy) * kSZ[s] + iz;
    ((int4*)(out + (size_t)s * OUT_STRIDE))[i] = make_int4(b, ix, iy, iz);
    bytemap[(size_t)kWB[s] * 32 + (unsigned)key] = 1;
  }
}

// 32 presence-bytes (each 0/1) -> 32-bit mask
__device__ __forceinline__ unsigned nib(unsigned u) {
  return (u | (u >> 7) | (u >> 14) | (u >> 21)) & 0xFu;
}
__device__ __forceinline__ unsigned word_from_bytes(const uint4* p) {
  uint4 a = p[0], b = p[1];
  return nib(a.x) | (nib(a.y) << 4) | (nib(a.z) << 8) | (nib(a.w) << 12) |
         (nib(b.x) << 16) | (nib(b.y) << 20) | (nib(b.z) << 24) | (nib(b.w) << 28);
}

// ---- scan stage 1: bytes -> {bits, chunk-local prefix} pairs + raw chunk sums
__global__ void scan1_kernel(const uint4* __restrict__ bytemap,
                             uint2* __restrict__ bw,
                             unsigned* __restrict__ bsums) {
  __shared__ unsigned sh[256];
  int tid = threadIdx.x;
  int base = blockIdx.x * 2048 + tid * 8;
  unsigned c[8], m[8];
  unsigned sum = 0;
#pragma unroll
  for (int j = 0; j < 8; ++j) {
    c[j] = sum;
    int w = base + j;
    m[j] = (w < W_TOTAL) ? word_from_bytes(bytemap + (size_t)w * 2) : 0u;
    sum += (unsigned)__popc(m[j]);
  }
  sh[tid] = sum;
  __syncthreads();
  for (int off = 1; off < 256; off <<= 1) {
    unsigned v = (tid >= off) ? sh[tid - off] : 0u;
    __syncthreads();
    sh[tid] += v;
    __syncthreads();
  }
  unsigned tbase = sh[tid] - sum;
#pragma unroll
  for (int j = 0; j < 8; ++j) {
    int w = base + j;
    if (w < W_TOTAL) bw[w] = make_uint2(m[j], tbase + c[j]);
  }
  if (tid == 0) bsums[blockIdx.x] = sh[255];
}

// ---- scan stage 2: exclusive chunk-sum scan; precompute region bases:
//      bsums[520+s] = full prefix at kWB[s] (s=0..4), bsums[525] = grand total
__global__ void scan2_kernel(const uint2* __restrict__ bw,
                             unsigned* __restrict__ bsums) {
  __shared__ unsigned sh[1024];
  int t = threadIdx.x;
  unsigned v = (t < SCAN_BLOCKS) ? bsums[t] : 0u;
  sh[t] = v;
  __syncthreads();
  for (int off = 1; off < 1024; off <<= 1) {
    unsigned u = (t >= off) ? sh[t - off] : 0u;
    __syncthreads();
    sh[t] += u;
    __syncthreads();
  }
  if (t < SCAN_BLOCKS) bsums[t] = sh[t] - v;       // exclusive
  if (t == SCAN_BLOCKS - 1) bsums[525] = sh[t];    // grand total
  if (t < 5) {
    int w = kWB[t];
    int c = w >> 11;
    unsigned chunkex = (c == 0) ? 0u : sh[c - 1];
    bsums[520 + t] = bw[w].y + chunkex;            // region base prefix
  }
}

// ---- emit: fused inverse / scatter / padfill (inv first: latency-bound)
__global__ void emit_kernel(const float4* __restrict__ pts,
                            const int* __restrict__ bidx,
                            const uint2* __restrict__ bw,
                            const unsigned* __restrict__ bsums,
                            int* __restrict__ out) {
  int blk = blockIdx.x;
  if (blk < INV_BLOCKS) {
    // --- inverse: recompute keys from points, rank via bitmap prefix
    int i = blk * 256 + threadIdx.x;
    if (i >= NPTS) return;
    float4 p = pts[i];
    float rho = __fsqrt_rn(__fadd_rn(__fmul_rn(p.x, p.x), __fmul_rn(p.y, p.y)));
    float phi = (float)atan2((double)p.y, (double)p.x);
    float zz = p.z;
    int b = bidx[i];
    const float PI_F = 3.14159265f;
    const float CROP1 = PI_F + PI_F;
#pragma unroll
    for (int s = 0; s < 5; ++s) {
      int ix = (int)__fdiv_rn(__fmul_rn(kSSX[s], rho), 50.0f);
      int iy = (int)__fdiv_rn(__fmul_rn(kSSY[s], __fsub_rn(phi, -PI_F)), CROP1);
      int iz = (int)__fdiv_rn(__fmul_rn(kSSZ[s], __fsub_rn(zz, -4.0f)), 6.0f);
      unsigned k = (unsigned)(((b * kSX[s] + ix) * kSY[s] + iy) * kSZ[s] + iz);
      int w = kWB[s] + (int)(k >> 5);
      uint2 v = bw[w];                       // one 8B gather: {bits, prefix}
      unsigned r = v.y + bsums[w >> 11] - bsums[520 + s] +
                   (unsigned)__popc(v.x & ((1u << (k & 31)) - 1u));
      out[(size_t)s * OUT_STRIDE + 4 * NPTS + i] = (int)r;
    }
  } else if (blk < INV_BLOCKS + SCAT_BLOCKS) {
    // --- scatter: decompose each present key into coors[rank]
    int w = (blk - INV_BLOCKS) * 256 + threadIdx.x;
    if (w >= W_TOTAL) return;
    uint2 v = bw[w];
    unsigned word = v.x;
    if (!word) return;
    int s, wb;
    unsigned sx, sy, sz;
    if      (w >= kWB[4]) { s = 4; wb = kWB[4]; sx = 481; sy = 361; sz = 33; }
    else if (w >= kWB[3]) { s = 3; wb = kWB[3]; sx = 31;  sy = 24;  sz = 3;  }
    else if (w >= kWB[2]) { s = 2; wb = kWB[2]; sx = 61;  sy = 46;  sz = 5;  }
    else if (w >= kWB[1]) { s = 1; wb = kWB[1]; sx = 121; sy = 91;  sz = 9;  }
    else                  { s = 0; wb = 0;      sx = 241; sy = 181; sz = 17; }
    unsigned rank = v.y + bsums[w >> 11] - bsums[520 + s];
    int4* coors = (int4*)(out + (size_t)s * OUT_STRIDE + 5 * NPTS);
    unsigned kbase = (unsigned)(w - wb) * 32u;
    while (word) {
      int bit = __ffs(word) - 1;
      word &= word - 1;
      unsigned k = kbase + (unsigned)bit;
      unsigned z = k % sz; unsigned t = k / sz;
      unsigned y = t % sy; t /= sy;
      unsigned x = t % sx; unsigned b = t / sx;
      coors[rank++] = make_int4((int)b, (int)z, (int)y, (int)x);
    }
  } else {
    // --- pad fill: rows >= uniq_count get the fill_value=-1 decode
    int idx = (blk - INV_BLOCKS - SCAT_BLOCKS) * 256 + threadIdx.x;
    if (idx >= 5 * NPTS) return;
    int s = idx / NPTS;
    int r = idx - s * NPTS;
    unsigned uniq = ((s == 4) ? bsums[525] : bsums[520 + s + 1]) - bsums[520 + s];
    if ((unsigned)r < uniq) return;
    ((int4*)(out + (size_t)s * OUT_STRIDE + 5 * NPTS))[r] =
        make_int4(-1, kSZ[s] - 1, kSY[s] - 1, kSX[s] - 1);
  }
}

extern "C" void kernel_launch(void* const* d_in, const int* in_sizes, int n_in,
                              void* d_out, int out_size, void* d_ws, size_t ws_size,
                              hipStream_t stream) {
  const float4* pts = (const float4*)d_in[0];
  const int* bidx = (const int*)d_in[1];
  int* out = (int*)d_out;

  uint2* bw       = (uint2*)d_ws;               // W_TOTAL uint2 (6.6 MB)
  unsigned* bsums = (unsigned*)(bw + W_TOTAL);  // 1024 u32 (chunk sums + bases)
  unsigned char* bytemap = (unsigned char*)(bsums + 1024);  // 26.4 MB
  // total ws use: ~33 MB (proven available)

  zero_kernel<<<(int)((BM_U4 + 255) / 256), 256, 0, stream>>>((uint4*)bytemap);
  mark_kernel<<<(NPTS + 255) / 256, 256, 0, stream>>>(pts, bidx, out, bytemap);
  scan1_kernel<<<SCAN_BLOCKS, 256, 0, stream>>>((const uint4*)bytemap, bw, bsums);
  scan2_kernel<<<1, 1024, 0, stream>>>(bw, bsums);
  emit_kernel<<<EMIT_BLOCKS, 256, 0, stream>>>(pts, bidx, bw, bsums, out);
}